// Round 2
// baseline (60.098 us; speedup 1.0000x reference)
//
#include <hip/hip_runtime.h>
#include <hip/hip_bf16.h>

#define L_CLS 2048
#define D_DIM 512
#define B_SZ  64
#define T_SZ  512
#define NT    511           // T-1 transitions per sequence
#define NOUT  (B_SZ * NT)   // 32704
#define NCHUNK 32           // col chunks in lse_partial (64 cols each)

typedef __attribute__((ext_vector_type(8))) short bf16x8;
typedef __attribute__((ext_vector_type(4))) float f32x4;
typedef __attribute__((ext_vector_type(4))) float float4v;

static __device__ __forceinline__ float bits2f(unsigned short u) {
    union { unsigned int i; float f; } v; v.i = ((unsigned int)u) << 16; return v.f;
}

// ---------------------------------------------------------------- conv kernel
// f32 -> bf16, vectorized: each thread converts 8 elements of BOTH tables.
__global__ void conv_bf16(const float* __restrict__ srcE, const float* __restrict__ tgtE,
                          __hip_bfloat16* __restrict__ Sb, __hip_bfloat16* __restrict__ Tb) {
    int i = blockIdx.x * blockDim.x + threadIdx.x;   // i indexes groups of 8
    if (i >= (L_CLS * D_DIM) / 8) return;
    const float4v* s4 = reinterpret_cast<const float4v*>(srcE) + i * 2;
    const float4v* t4 = reinterpret_cast<const float4v*>(tgtE) + i * 2;
    float4v s0 = s4[0], s1 = s4[1];
    float4v t0 = t4[0], t1 = t4[1];
    bf16x8 so, to;
#pragma unroll
    for (int j = 0; j < 4; ++j) {
        so[j]     = (short)__bfloat16_as_ushort(__float2bfloat16(s0[j]));
        so[j + 4] = (short)__bfloat16_as_ushort(__float2bfloat16(s1[j]));
        to[j]     = (short)__bfloat16_as_ushort(__float2bfloat16(t0[j]));
        to[j + 4] = (short)__bfloat16_as_ushort(__float2bfloat16(t1[j]));
    }
    reinterpret_cast<bf16x8*>(Sb)[i] = so;
    reinterpret_cast<bf16x8*>(Tb)[i] = to;
}

// ------------------------------------------------------- fused GEMM + row-LSE
// grid (32, 32): blockIdx.x = 64-row block of S, blockIdx.y = 64-col chunk of T.
// 256 threads = 4 waves; wave w owns rows [bx*64 + w*16, +16), computes 4
// col-tiles (16x16 each), keeps all 16 logits/lane in regs, then max->sum.
__launch_bounds__(256)
__global__ void lse_partial(const __hip_bfloat16* __restrict__ Sb,
                            const __hip_bfloat16* __restrict__ Tb,
                            float* __restrict__ pmax, float* __restrict__ psum) {
    const int wave = threadIdx.x >> 6;
    const int lane = threadIdx.x & 63;
    const int R = blockIdx.x * 64 + wave * 16;   // source-row base of this wave
    const int C = blockIdx.y * 64;               // target-col chunk base
    const int lr = lane & 15;                    // row (A) / col (B) within 16
    const int lk = (lane >> 4) * 8;              // k offset within the K=32 step

    // A fragments for all 16 k-steps (rows R+lr, 8 contiguous k-elems each)
    bf16x8 a[16];
    const __hip_bfloat16* arow = Sb + (R + lr) * D_DIM + lk;
#pragma unroll
    for (int ks = 0; ks < 16; ++ks)
        a[ks] = *reinterpret_cast<const bf16x8*>(arow + ks * 32);

    f32x4 acc[4];
#pragma unroll
    for (int ct = 0; ct < 4; ++ct) {
        const __hip_bfloat16* brow = Tb + (C + ct * 16 + lr) * D_DIM + lk;
        f32x4 c = {0.f, 0.f, 0.f, 0.f};
#pragma unroll
        for (int ks = 0; ks < 16; ++ks) {
            bf16x8 b = *reinterpret_cast<const bf16x8*>(brow + ks * 32);
            c = __builtin_amdgcn_mfma_f32_16x16x32_bf16(a[ks], b, c, 0, 0, 0);
        }
        acc[ct] = c;
    }

    // Two-phase LSE over this lane's 16 logits (4 rows x 4 col-tiles).
    // D layout: col = lane&15, row = (lane>>4)*4 + i.
    float m[4], s[4];
#pragma unroll
    for (int i = 0; i < 4; ++i) {
        m[i] = fmaxf(fmaxf(acc[0][i], acc[1][i]), fmaxf(acc[2][i], acc[3][i]));
        s[i] = 0.f;
#pragma unroll
        for (int ct = 0; ct < 4; ++ct)
            s[i] += __expf(acc[ct][i] - m[i]);
    }

    // Reduce (max,sum) across the 16 lanes that share rows (same lane>>4 group).
#pragma unroll
    for (int off = 1; off < 16; off <<= 1) {
#pragma unroll
        for (int i = 0; i < 4; ++i) {
            float om = __shfl_xor(m[i], off);
            float os = __shfl_xor(s[i], off);
            float mn = fmaxf(m[i], om);
            s[i] = s[i] * __expf(m[i] - mn) + os * __expf(om - mn);
            m[i] = mn;
        }
    }

    if (lr == 0) {
        int g = lane >> 4;
#pragma unroll
        for (int i = 0; i < 4; ++i) {
            int row = R + g * 4 + i;
            pmax[row * NCHUNK + blockIdx.y] = m[i];
            psum[row * NCHUNK + blockIdx.y] = s[i];
        }
    }
}

// ------------------------------------------------------------ combine chunks
__global__ void lse_final(const float* __restrict__ pmax, const float* __restrict__ psum,
                          float* __restrict__ lse) {
    int row = blockIdx.x * blockDim.x + threadIdx.x;
    if (row < L_CLS) {
        float m = -INFINITY;
#pragma unroll
        for (int c = 0; c < NCHUNK; ++c)
            m = fmaxf(m, pmax[row * NCHUNK + c]);
        float s = 0.f;
#pragma unroll
        for (int c = 0; c < NCHUNK; ++c)
            s += psum[row * NCHUNK + c] * __expf(pmax[row * NCHUNK + c] - m);
        lse[row] = m + __logf(s);
    }
}

// --------------------------------------------------------------- gather-dots
// one wave per output element: scores[b,t] = dot(Sb[src], Tb[tgt]) - lse[src]
__launch_bounds__(256)
__global__ void scores_kernel(const int* __restrict__ labels,
                              const __hip_bfloat16* __restrict__ Sb,
                              const __hip_bfloat16* __restrict__ Tb,
                              const float* __restrict__ lse,
                              float* __restrict__ out) {
    const int wid  = blockIdx.x * 4 + (threadIdx.x >> 6);   // grid sized exactly
    const int lane = threadIdx.x & 63;
    const int b = wid / NT;
    const int t = wid - b * NT;
    const int src = labels[b * T_SZ + t];
    const int tgt = labels[b * T_SZ + t + 1];

    bf16x8 sv = *reinterpret_cast<const bf16x8*>(Sb + src * D_DIM + lane * 8);
    bf16x8 tv = *reinterpret_cast<const bf16x8*>(Tb + tgt * D_DIM + lane * 8);
    float acc = 0.f;
#pragma unroll
    for (int j = 0; j < 8; ++j)
        acc += bits2f((unsigned short)sv[j]) * bits2f((unsigned short)tv[j]);

#pragma unroll
    for (int off = 32; off; off >>= 1)
        acc += __shfl_xor(acc, off);

    if (lane == 0) out[wid] = acc - lse[src];
}

// ------------------------------------------------------------------- launcher
extern "C" void kernel_launch(void* const* d_in, const int* in_sizes, int n_in,
                              void* d_out, int out_size, void* d_ws, size_t ws_size,
                              hipStream_t stream) {
    const int*   labels = (const int*)d_in[0];
    const float* srcE   = (const float*)d_in[1];
    const float* tgtE   = (const float*)d_in[2];
    float*       out    = (float*)d_out;

    char* ws = (char*)d_ws;
    __hip_bfloat16* Sb = (__hip_bfloat16*)ws;                       // 2 MB
    __hip_bfloat16* Tb = Sb + L_CLS * D_DIM;                        // 2 MB
    float* pmax = (float*)(ws + (size_t)2 * L_CLS * D_DIM * 2);     // 256 KB
    float* psum = pmax + L_CLS * NCHUNK;                            // 256 KB
    float* lse  = psum + L_CLS * NCHUNK;                            // 8 KB

    conv_bf16<<<(L_CLS * D_DIM / 8 + 255) / 256, 256, 0, stream>>>(srcE, tgtE, Sb, Tb);
    lse_partial<<<dim3(32, NCHUNK), 256, 0, stream>>>(Sb, Tb, pmax, psum);
    lse_final<<<(L_CLS + 255) / 256, 256, 0, stream>>>(pmax, psum, lse);
    scores_kernel<<<NOUT / 4, 256, 0, stream>>>(labels, Sb, Tb, lse, out);
}

// Round 3
// 43.857 us; speedup vs baseline: 1.3703x; 1.3703x over previous
//
#include <hip/hip_runtime.h>
#include <hip/hip_bf16.h>

#define L_CLS 2048
#define D_DIM 512
#define B_SZ  64
#define T_SZ  512
#define NT    511           // T-1 transitions per sequence
#define NOUT  (B_SZ * NT)   // 32704
#define NCHUNK 32           // col chunks in lse_partial (64 cols each)
#define LDS_STRIDE 136      // 128 bf16 + 4x16B pad -> 272 B rows (bank-spread)

typedef __attribute__((ext_vector_type(8))) short bf16x8;
typedef __attribute__((ext_vector_type(4))) float f32x4;
typedef __attribute__((ext_vector_type(4))) float float4v;

static __device__ __forceinline__ short f2bf(float x) {
    return (short)__bfloat16_as_ushort(__float2bfloat16(x));
}

// ------------------------------------------------- fused conv + GEMM + row-LSE
// grid (32, 32): blockIdx.x = 64-row block of S, blockIdx.y = 64-col chunk of T.
// 256 threads = 4 waves; wave w owns rows [bx*64 + w*16, +16).
// B chunk (64 cols x 512 k) is staged f32->bf16 into LDS in 4 K-slices of 128,
// shared by all 4 waves. A fragments converted inline into registers.
__launch_bounds__(256)
__global__ void lse_partial(const float* __restrict__ srcE,
                            const float* __restrict__ tgtE,
                            float* __restrict__ pmax, float* __restrict__ psum) {
    __shared__ __hip_bfloat16 Blds[64 * LDS_STRIDE];   // 17408 B

    const int tid  = threadIdx.x;
    const int wave = tid >> 6;
    const int lane = tid & 63;
    const int R = blockIdx.x * 64 + wave * 16;   // source-row base of this wave
    const int C = blockIdx.y * 64;               // target-col chunk base
    const int lr = lane & 15;                    // row (A) / col (B) within 16
    const int hi = lane >> 4;                    // k-group 0..3
    const int lk = hi * 8;                       // k offset within the K=32 step

    // A fragments for all 16 k-steps: rows R+lr, inline f32->bf16.
    bf16x8 a[16];
    const float* arow = srcE + (R + lr) * D_DIM + lk;
#pragma unroll
    for (int j = 0; j < 16; ++j) {
        const float4v* g = reinterpret_cast<const float4v*>(arow + j * 32);
        float4v x0 = g[0], x1 = g[1];
        bf16x8 w;
#pragma unroll
        for (int e = 0; e < 4; ++e) { w[e] = f2bf(x0[e]); w[e + 4] = f2bf(x1[e]); }
        a[j] = w;
    }

    f32x4 acc0 = {0.f,0.f,0.f,0.f}, acc1 = {0.f,0.f,0.f,0.f};
    f32x4 acc2 = {0.f,0.f,0.f,0.f}, acc3 = {0.f,0.f,0.f,0.f};

    const int srow = tid >> 4;       // staging: this thread's B row (0..63) per i? no: p>>4
#pragma unroll
    for (int s = 0; s < 4; ++s) {    // K-slices of 128
        // ---- stage 64 rows x 128 k of T chunk into LDS (f32 -> bf16) ----
#pragma unroll
        for (int i = 0; i < 4; ++i) {
            int p   = tid + 256 * i;         // 0..1023
            int row = p >> 4;                // 0..63
            int grp = p & 15;                // 16-elem... 8-elem group 0..15
            const float4v* g = reinterpret_cast<const float4v*>(
                tgtE + (C + row) * D_DIM + s * 128 + grp * 8);
            float4v x0 = g[0], x1 = g[1];
            bf16x8 w;
#pragma unroll
            for (int e = 0; e < 4; ++e) { w[e] = f2bf(x0[e]); w[e + 4] = f2bf(x1[e]); }
            *reinterpret_cast<bf16x8*>(&Blds[row * LDS_STRIDE + grp * 8]) = w;
        }
        __syncthreads();

        // ---- 4 col-tiles x 4 K-steps of MFMA from LDS ----
#pragma unroll
        for (int ks = 0; ks < 4; ++ks) {
            const int off = ks * 32 + lk;
            bf16x8 b0 = *reinterpret_cast<const bf16x8*>(&Blds[(0*16 + lr) * LDS_STRIDE + off]);
            bf16x8 b1 = *reinterpret_cast<const bf16x8*>(&Blds[(1*16 + lr) * LDS_STRIDE + off]);
            bf16x8 b2 = *reinterpret_cast<const bf16x8*>(&Blds[(2*16 + lr) * LDS_STRIDE + off]);
            bf16x8 b3 = *reinterpret_cast<const bf16x8*>(&Blds[(3*16 + lr) * LDS_STRIDE + off]);
            acc0 = __builtin_amdgcn_mfma_f32_16x16x32_bf16(a[s*4+ks], b0, acc0, 0, 0, 0);
            acc1 = __builtin_amdgcn_mfma_f32_16x16x32_bf16(a[s*4+ks], b1, acc1, 0, 0, 0);
            acc2 = __builtin_amdgcn_mfma_f32_16x16x32_bf16(a[s*4+ks], b2, acc2, 0, 0, 0);
            acc3 = __builtin_amdgcn_mfma_f32_16x16x32_bf16(a[s*4+ks], b3, acc3, 0, 0, 0);
        }
        __syncthreads();
    }

    // Two-phase LSE over this lane's 16 logits (4 rows x 4 col-tiles).
    // D layout: col = lane&15, row = hi*4 + i.
    float m[4], ssum[4];
#pragma unroll
    for (int i = 0; i < 4; ++i) {
        m[i] = fmaxf(fmaxf(acc0[i], acc1[i]), fmaxf(acc2[i], acc3[i]));
        ssum[i] = __expf(acc0[i] - m[i]) + __expf(acc1[i] - m[i])
                + __expf(acc2[i] - m[i]) + __expf(acc3[i] - m[i]);
    }

    // Reduce (max,sum) across the 16 lanes that share rows (same hi group).
#pragma unroll
    for (int off = 1; off < 16; off <<= 1) {
#pragma unroll
        for (int i = 0; i < 4; ++i) {
            float om = __shfl_xor(m[i], off);
            float os = __shfl_xor(ssum[i], off);
            float mn = fmaxf(m[i], om);
            ssum[i] = ssum[i] * __expf(m[i] - mn) + os * __expf(om - mn);
            m[i] = mn;
        }
    }

    if (lr == 0) {
#pragma unroll
        for (int i = 0; i < 4; ++i) {
            int row = R + hi * 4 + i;
            pmax[row * NCHUNK + blockIdx.y] = m[i];
            psum[row * NCHUNK + blockIdx.y] = ssum[i];
        }
    }
}

// ------------------------------------------- gather-dots with inline LSE-final
// one wave per output: scores[b,t] = dot_f32(S[src], T[tgt]) - lse(src)
// lse recomputed from the 32 partials: lanes 0..31 each hold one (max,sum),
// identity elements elsewhere; a single 64-lane butterfly reduces both the
// dot partial sums and the (max,sum) pair.
__launch_bounds__(256)
__global__ void scores_kernel(const int* __restrict__ labels,
                              const float* __restrict__ srcE,
                              const float* __restrict__ tgtE,
                              const float* __restrict__ pmax,
                              const float* __restrict__ psum,
                              float* __restrict__ out) {
    const int wid  = blockIdx.x * 4 + (threadIdx.x >> 6);   // grid sized exactly
    const int lane = threadIdx.x & 63;
    const int b = wid / NT;
    const int t = wid - b * NT;
    const int src = labels[b * T_SZ + t];
    const int tgt = labels[b * T_SZ + t + 1];

    const float4v* sp = reinterpret_cast<const float4v*>(srcE + src * D_DIM + lane * 8);
    const float4v* tp = reinterpret_cast<const float4v*>(tgtE + tgt * D_DIM + lane * 8);
    float4v s0 = sp[0], s1 = sp[1];
    float4v t0 = tp[0], t1 = tp[1];
    float acc = 0.f;
#pragma unroll
    for (int j = 0; j < 4; ++j) acc += s0[j] * t0[j] + s1[j] * t1[j];

    float pm = (lane < NCHUNK) ? pmax[src * NCHUNK + lane] : -INFINITY;
    float ps = (lane < NCHUNK) ? psum[src * NCHUNK + lane] : 0.f;

#pragma unroll
    for (int off = 32; off; off >>= 1) {
        acc += __shfl_xor(acc, off);
        float om = __shfl_xor(pm, off);
        float os = __shfl_xor(ps, off);
        float mn = fmaxf(pm, om);
        ps = ps * __expf(pm - mn) + os * __expf(om - mn);
        pm = mn;
    }

    if (lane == 0) out[wid] = acc - (pm + __logf(ps));
}

// ------------------------------------------------------------------- launcher
extern "C" void kernel_launch(void* const* d_in, const int* in_sizes, int n_in,
                              void* d_out, int out_size, void* d_ws, size_t ws_size,
                              hipStream_t stream) {
    const int*   labels = (const int*)d_in[0];
    const float* srcE   = (const float*)d_in[1];
    const float* tgtE   = (const float*)d_in[2];
    float*       out    = (float*)d_out;

    char* ws = (char*)d_ws;
    float* pmax = (float*)ws;                    // 256 KB
    float* psum = pmax + L_CLS * NCHUNK;         // 256 KB

    lse_partial<<<dim3(32, NCHUNK), 256, 0, stream>>>(srcE, tgtE, pmax, psum);
    scores_kernel<<<NOUT / 4, 256, 0, stream>>>(labels, srcE, tgtE, pmax, psum, out);
}

// Round 6
// 31.788 us; speedup vs baseline: 1.8906x; 1.3797x over previous
//
#include <hip/hip_runtime.h>
#include <hip/hip_bf16.h>

#define L_CLS 2048
#define D_DIM 512
#define T_SZ  512
#define NT    511              // T-1 transitions per sequence
#define NOUT  (64 * NT)        // 32704
#define NCHUNK 32              // 64-col chunks
#define LDS_STRIDE 136         // 128 bf16 + pad -> 272 B rows
#define LOG2E 1.4426950408889634f
#define LN2   0.6931471805599453f
#define SHIFT 128.0f           // fixed exponent shift: sum 2^(x*log2e - SHIFT)

typedef __attribute__((ext_vector_type(8))) short bf16x8;
typedef __attribute__((ext_vector_type(4))) float f32x4;

static __device__ __forceinline__ short f2bf(float x) {
    return (short)__bfloat16_as_ushort(__float2bfloat16(x));
}

// -------------------------------------------- fused conv + GEMM + partial sums
// grid (16, 32): blockIdx.x -> two 64-row S-blocks (x, x+16), blockIdx.y ->
// 64-col T-chunk. 256 thr = 4 waves; wave w owns rows [.. + w*16, +16) of each
// block. B chunk staged f32->bf16 into LDS in 4 K-slices of 128, shared by
// both row-blocks (halves staging vs one-block-per-WG). Logits written to M;
// per-(row,chunk) fixed-shift exp sums to psum.
__launch_bounds__(256)
__global__ void gemm_lse(const float* __restrict__ srcE,
                         const float* __restrict__ tgtE,
                         float* __restrict__ psum,
                         float* __restrict__ M, int useM) {
    __shared__ __hip_bfloat16 Blds[64 * LDS_STRIDE];   // 17408 B

    const int tid  = threadIdx.x;
    const int wave = tid >> 6;
    const int lane = tid & 63;
    const int lr   = lane & 15;
    const int hi   = lane >> 4;
    const int by   = blockIdx.y;
    const int C    = by * 64;
    const int R0   = blockIdx.x * 64 + wave * 16;            // row-block 0
    const int R1   = (blockIdx.x + 16) * 64 + wave * 16;     // row-block 1

    f32x4 acc[2][4];
#pragma unroll
    for (int rb = 0; rb < 2; ++rb)
#pragma unroll
        for (int ct = 0; ct < 4; ++ct) acc[rb][ct] = (f32x4){0.f, 0.f, 0.f, 0.f};

#pragma unroll
    for (int s = 0; s < 4; ++s) {    // K-slices of 128
        // ---- stage 64 rows x 128 k of T chunk into LDS (f32 -> bf16) ----
#pragma unroll
        for (int i = 0; i < 4; ++i) {
            int p   = tid + 256 * i;         // 0..1023
            int row = p >> 4;                // 0..63
            int grp = p & 15;                // 8-elem group 0..15
            const f32x4* g = reinterpret_cast<const f32x4*>(
                tgtE + (C + row) * D_DIM + s * 128 + grp * 8);
            f32x4 x0 = g[0], x1 = g[1];
            bf16x8 w;
#pragma unroll
            for (int e = 0; e < 4; ++e) { w[e] = f2bf(x0[e]); w[e + 4] = f2bf(x1[e]); }
            *reinterpret_cast<bf16x8*>(&Blds[row * LDS_STRIDE + grp * 8]) = w;
        }
        __syncthreads();

        // ---- both row-blocks: A frags for this slice, then 4x4 MFMAs ----
#pragma unroll
        for (int rb = 0; rb < 2; ++rb) {
            const int R = rb ? R1 : R0;
            bf16x8 a[4];
            const float* arow = srcE + (R + lr) * D_DIM + s * 128 + hi * 8;
#pragma unroll
            for (int ks = 0; ks < 4; ++ks) {
                const f32x4* g = reinterpret_cast<const f32x4*>(arow + ks * 32);
                f32x4 x0 = g[0], x1 = g[1];
                bf16x8 v;
#pragma unroll
                for (int e = 0; e < 4; ++e) { v[e] = f2bf(x0[e]); v[e + 4] = f2bf(x1[e]); }
                a[ks] = v;
            }
#pragma unroll
            for (int ks = 0; ks < 4; ++ks) {
                const int off = ks * 32 + hi * 8;
#pragma unroll
                for (int ct = 0; ct < 4; ++ct) {
                    bf16x8 b = *reinterpret_cast<const bf16x8*>(
                        &Blds[(ct * 16 + lr) * LDS_STRIDE + off]);
                    acc[rb][ct] = __builtin_amdgcn_mfma_f32_16x16x32_bf16(
                        a[ks], b, acc[rb][ct], 0, 0, 0);
                }
            }
        }
        __syncthreads();
    }

    // ---- epilogue: M writes + fixed-shift exp sums ----
    // D layout: col = C + ct*16 + lr, row = R + hi*4 + i.
#pragma unroll
    for (int rb = 0; rb < 2; ++rb) {
        const int R = rb ? R1 : R0;
        if (useM) {
#pragma unroll
            for (int i = 0; i < 4; ++i) {
                size_t rg = (size_t)(R + hi * 4 + i) * L_CLS + C + lr;
                M[rg]      = acc[rb][0][i];
                M[rg + 16] = acc[rb][1][i];
                M[rg + 32] = acc[rb][2][i];
                M[rg + 48] = acc[rb][3][i];
            }
        }
        float p[4];
#pragma unroll
        for (int i = 0; i < 4; ++i) {
            p[i] = exp2f(acc[rb][0][i] * LOG2E - SHIFT)
                 + exp2f(acc[rb][1][i] * LOG2E - SHIFT)
                 + exp2f(acc[rb][2][i] * LOG2E - SHIFT)
                 + exp2f(acc[rb][3][i] * LOG2E - SHIFT);
        }
#pragma unroll
        for (int off = 1; off < 16; off <<= 1)
#pragma unroll
            for (int i = 0; i < 4; ++i) p[i] += __shfl_xor(p[i], off);
        if (lr == 0) {
#pragma unroll
            for (int i = 0; i < 4; ++i)
                psum[(R + hi * 4 + i) * NCHUNK + by] = p[i];
        }
    }
}

// -------------------------------------------------------------- gather scores
// one thread per output: out = M[src,tgt] - lse[src], lse from 32 partials.
__launch_bounds__(256)
__global__ void scores_gather(const int* __restrict__ labels,
                              const float* __restrict__ psum,
                              const float* __restrict__ M,
                              float* __restrict__ out) {
    int o = blockIdx.x * 256 + threadIdx.x;
    if (o >= NOUT) return;
    int b = o / NT;
    int t = o - b * NT;
    int src = labels[b * T_SZ + t];
    int tgt = labels[b * T_SZ + t + 1];

    const f32x4* p4 = reinterpret_cast<const f32x4*>(psum) + src * (NCHUNK / 4);
    f32x4 sv = {0.f, 0.f, 0.f, 0.f};
#pragma unroll
    for (int c = 0; c < NCHUNK / 4; ++c) {
        f32x4 v = p4[c];
        sv[0] += v[0]; sv[1] += v[1]; sv[2] += v[2]; sv[3] += v[3];
    }
    float S = (sv[0] + sv[1]) + (sv[2] + sv[3]);
    float lse = (log2f(S) + SHIFT) * LN2;
    out[o] = M[(size_t)src * L_CLS + tgt] - lse;
}

// -------------------------------------- fallback: dot-product scores (no M ws)
__launch_bounds__(256)
__global__ void scores_dot(const int* __restrict__ labels,
                           const float* __restrict__ srcE,
                           const float* __restrict__ tgtE,
                           const float* __restrict__ psum,
                           float* __restrict__ out) {
    const int wid  = blockIdx.x * 4 + (threadIdx.x >> 6);
    const int lane = threadIdx.x & 63;
    const int b = wid / NT;
    const int t = wid - b * NT;
    const int src = labels[b * T_SZ + t];
    const int tgt = labels[b * T_SZ + t + 1];

    const f32x4* sp = reinterpret_cast<const f32x4*>(srcE + src * D_DIM + lane * 8);
    const f32x4* tp = reinterpret_cast<const f32x4*>(tgtE + tgt * D_DIM + lane * 8);
    f32x4 s0 = sp[0], s1 = sp[1];
    f32x4 t0 = tp[0], t1 = tp[1];
    float acc = 0.f;
#pragma unroll
    for (int j = 0; j < 4; ++j) acc += s0[j] * t0[j] + s1[j] * t1[j];
    float ps = (lane < NCHUNK) ? psum[src * NCHUNK + lane] : 0.f;
#pragma unroll
    for (int off = 32; off; off >>= 1) {
        acc += __shfl_xor(acc, off);
        ps  += __shfl_xor(ps, off);
    }
    if (lane == 0) out[wid] = acc - (log2f(ps) + SHIFT) * LN2;
}

// ------------------------------------------------------------------- launcher
extern "C" void kernel_launch(void* const* d_in, const int* in_sizes, int n_in,
                              void* d_out, int out_size, void* d_ws, size_t ws_size,
                              hipStream_t stream) {
    const int*   labels = (const int*)d_in[0];
    const float* srcE   = (const float*)d_in[1];
    const float* tgtE   = (const float*)d_in[2];
    float*       out    = (float*)d_out;

    float* psum = (float*)d_ws;                   // 256 KB
    float* M    = psum + L_CLS * NCHUNK;          // 16 MB

    size_t need = ((size_t)L_CLS * NCHUNK + (size_t)L_CLS * L_CLS) * sizeof(float);
    int useM = (ws_size >= need) ? 1 : 0;

    gemm_lse<<<dim3(16, NCHUNK), 256, 0, stream>>>(srcE, tgtE, psum, M, useM);
    if (useM)
        scores_gather<<<(NOUT + 255) / 256, 256, 0, stream>>>(labels, psum, M, out);
    else
        scores_dot<<<NOUT / 4, 256, 0, stream>>>(labels, srcE, tgtE, psum, out);
}